// Round 11
// baseline (257.549 us; speedup 1.0000x reference)
//
#include <hip/hip_runtime.h>
#include <hip/hip_bf16.h>
#include <stdint.h>

// z_e (32,64,64,64) f32, codebook (512,64) f32.
// d_out (f32): [0..8388607] z_q (B,C,H,W); [8388608] loss; [8388609..] indices as float.
#define NPIX 131072
#define CDIM 64
#define KCODES 512
#define ZQ_SIZE 8388608
#define LOSS_OFF 8388608
#define IDXOUT_OFF 8388609
#define CH_STRIDE 4096
#define B_STRIDE 262144
#define MARGIN_UNITS 256       // 256 * 2^-22 ~ 6.1e-5 score gap: covers ref f32 grid noise
#define SCALE 4194304.0f       // 2^22
#define BIAS 0.5f

typedef __attribute__((ext_vector_type(8))) short short8v;   // 8 bf16
typedef __attribute__((ext_vector_type(16))) float f32x16;
typedef __attribute__((ext_vector_type(4))) float f32x4;
typedef __attribute__((ext_vector_type(4))) int i32x4;

// ws layout:
//   0       double loss
//   64      float  c2_ref[512]   (numpy pairwise-8 order, for exact resolve)
//   2112    float  c2fix[512]    ((||c||^2 + 0.5) * 2^22)
//   4160    ushort cb_hi chunks  [g=0..7][code][8 bf16], scaled 2^11  (65536 B)
//   69696   ushort cb_lo chunks  same layout, residual scaled 2^11    (65536 B)
//   135232  float  cbT[64][512]  transposed f32 codebook (131072 B) — coalesced resolve reads
#define WS_C2REF 64
#define WS_C2FIX 2112
#define WS_CBHI  4160
#define WS_CBLO  69696
#define WS_CBT   135232

__device__ __forceinline__ uint32_t f2bf_rne(float v) {
    uint32_t u = __float_as_uint(v);
    return (u + 0x7FFFu + ((u >> 16) & 1u)) >> 16;
}
__device__ __forceinline__ float bf2f(short s) {
    return __uint_as_float(((uint32_t)(unsigned short)s) << 16);
}

__global__ void k0_prep(const float* __restrict__ cb, char* __restrict__ ws) {
#pragma clang fp contract(off)
    int k = threadIdx.x;
    if (k >= KCODES) return;
    const float* cr = cb + (size_t)k * CDIM;
    float r[8];
    #pragma unroll
    for (int j = 0; j < 8; ++j) r[j] = cr[j] * cr[j];
    #pragma unroll
    for (int t = 1; t < 8; ++t)
        #pragma unroll
        for (int j = 0; j < 8; ++j) r[j] += cr[8 * t + j] * cr[8 * t + j];
    ((float*)(ws + WS_C2REF))[k] = ((r[0] + r[1]) + (r[2] + r[3])) + ((r[4] + r[5]) + (r[6] + r[7]));
    float acc = 0.f;
    #pragma unroll
    for (int i = 0; i < CDIM; ++i) acc = fmaf(cr[i], cr[i], acc);
    ((float*)(ws + WS_C2FIX))[k] = (acc + BIAS) * SCALE;
    unsigned short* hi = (unsigned short*)(ws + WS_CBHI);
    unsigned short* lo = (unsigned short*)(ws + WS_CBLO);
    #pragma unroll
    for (int g = 0; g < 8; ++g)
        #pragma unroll
        for (int j = 0; j < 8; ++j) {
            float cs = cr[g * 8 + j] * 2048.0f;
            uint32_t uh = f2bf_rne(cs);
            float l = cs - bf2f((short)uh);
            size_t o = ((size_t)(g * KCODES + k)) * 8 + j;
            hi[o] = (unsigned short)uh;
            lo[o] = (unsigned short)f2bf_rne(l);
        }
    // transposed exact f32 codebook: cbT[ch][code]  (coalesced across threads)
    float* cbT = (float*)(ws + WS_CBT);
    #pragma unroll
    for (int i = 0; i < CDIM; ++i) cbT[i * KCODES + k] = cr[i];
}

// Block = 256 contiguous pixels, 4 waves. Contiguous global streams via LDS tile;
// MFMA + min-track math identical to Round-8 (verified).
__global__ __launch_bounds__(256, 2) void k1_mfma(const float* __restrict__ z_e,
                                                  const float* __restrict__ cb,
                                                  char* __restrict__ ws,
                                                  float* __restrict__ out) {
#pragma clang fp contract(off)
    extern __shared__ char smem[];
    float (*zt)[260] = (float (*)[260])smem;          // [ch][px] +4 pad  (66560 B)
    int*    idxs = (int*)(smem + 66560);              // 1024 B
    float*  c2s  = (float*)(smem + 67584);            // 2048 B
    double* wls  = (double*)(smem + 69632);           // 32 B

    const int tid  = threadIdx.x;
    const int lane = tid & 63;
    const int wav  = tid >> 6;
    const int h    = lane >> 5;
    const int c    = lane & 31;

    const int pxblk = blockIdx.x * 256;
    const int b     = pxblk >> 12;
    const int hw0   = pxblk & 4095;
    const float* zbase = z_e + (size_t)b * B_STRIDE + hw0;

    // ---- Phase A: stage z tile (64ch x 256px) + c2fix to LDS
    {
        int px4 = lane * 4;
        #pragma unroll
        for (int p = 0; p < 16; ++p) {
            int ch = p * 4 + wav;
            f32x4 v = *(const f32x4*)(zbase + (size_t)ch * CH_STRIDE + px4);
            *(f32x4*)&zt[ch][px4] = v;
        }
        if (tid < 128)
            ((f32x4*)c2s)[tid] = ((const f32x4*)(ws + WS_C2FIX))[tid];
    }
    __syncthreads();

    // ---- Phase B: MFMA scores + min-track (identical math to Round 8)
    const int pw = wav * 64;

    short8v zh[2][4], zl[2][4];
    #pragma unroll
    for (int set = 0; set < 2; ++set) {
        int px = pw + set * 32 + c;
        #pragma unroll
        for (int s = 0; s < 4; ++s) {
            short8v vh, vl;
            #pragma unroll
            for (int j = 0; j < 8; ++j) {
                float zs = zt[s * 16 + h * 8 + j][px] * -4096.0f;
                uint32_t uh = f2bf_rne(zs);
                float l = zs - bf2f((short)uh);
                vh[j] = (short)uh;
                vl[j] = (short)f2bf_rne(l);
            }
            zh[set][s] = vh; zl[set][s] = vl;
        }
    }

    const short8v* hi_chunks = (const short8v*)(ws + WS_CBHI);
    const short8v* lo_chunks = (const short8v*)(ws + WS_CBLO);
    uint32_t m1[2] = {0xFFFFFFFFu, 0xFFFFFFFFu};
    uint32_t m2[2] = {0xFFFFFFFFu, 0xFFFFFFFFu};

    #pragma unroll
    for (int t = 0; t < 16; ++t) {
        short8v a[4], al[4];
        #pragma unroll
        for (int s = 0; s < 4; ++s) {
            int chunk = (2 * s + h) * KCODES + t * 32 + c;
            a[s]  = hi_chunks[chunk];
            al[s] = lo_chunks[chunk];
        }
        int rbase = t * 32 + 4 * h;
        f32x4 q0 = *(const f32x4*)(c2s + rbase + 0);
        f32x4 q1 = *(const f32x4*)(c2s + rbase + 8);
        f32x4 q2 = *(const f32x4*)(c2s + rbase + 16);
        f32x4 q3 = *(const f32x4*)(c2s + rbase + 24);

        #pragma unroll
        for (int set = 0; set < 2; ++set) {
            f32x16 acc;
            #pragma unroll
            for (int i = 0; i < 4; ++i) {
                acc[i] = q0[i]; acc[4 + i] = q1[i]; acc[8 + i] = q2[i]; acc[12 + i] = q3[i];
            }
            #pragma unroll
            for (int s = 0; s < 4; ++s)
                acc = __builtin_amdgcn_mfma_f32_32x32x16_bf16(a[s], zh[set][s], acc, 0, 0, 0);
            #pragma unroll
            for (int s = 0; s < 4; ++s)
                acc = __builtin_amdgcn_mfma_f32_32x32x16_bf16(a[s], zl[set][s], acc, 0, 0, 0);
            #pragma unroll
            for (int s = 0; s < 4; ++s)
                acc = __builtin_amdgcn_mfma_f32_32x32x16_bf16(al[s], zh[set][s], acc, 0, 0, 0);
            #pragma unroll
            for (int i = 0; i < 16; ++i) {
                uint32_t code = (uint32_t)(t * 32 + 4 * h + (i & 3) + 8 * (i >> 2));
                uint32_t u = (((uint32_t)acc[i]) << 9) | code;
                uint32_t mx = m1[set] > u ? m1[set] : u;
                m2[set] = m2[set] < mx ? m2[set] : mx;
                m1[set] = m1[set] < u ? m1[set] : u;
            }
        }
    }

    #pragma unroll
    for (int set = 0; set < 2; ++set) {
        uint32_t o1 = (uint32_t)__shfl_xor((int)m1[set], 32);
        uint32_t o2 = (uint32_t)__shfl_xor((int)m2[set], 32);
        uint32_t mx  = m1[set] > o1 ? m1[set] : o1;
        uint32_t mn2 = m2[set] < o2 ? m2[set] : o2;
        m2[set] = mn2 < mx ? mn2 : mx;
        m1[set] = m1[set] < o1 ? m1[set] : o1;
    }

    int  idxv[2]; bool flag[2];
    #pragma unroll
    for (int set = 0; set < 2; ++set) {
        idxv[set] = (int)(m1[set] & 0x1FFu);
        int gap = (int)((m2[set] >> 9) - (m1[set] >> 9));
        flag[set] = gap < MARGIN_UNITS;
    }

    // ---- in-wave exact resolve (reference f32 math), coalesced via cbT ----
    // Lane l evaluates codes {k*64+l : k=0..7}; loads cbT[i*512 + k*64 + lane]
    // are lane-contiguous (coalesced, L2-hot). z channels broadcast from LDS.
    {
        const float* c2r = (const float*)(ws + WS_C2REF);
        const float* cbT = (const float*)(ws + WS_CBT);
        #pragma unroll 1
        for (int set = 0; set < 2; ++set) {
            unsigned long long mask = __ballot(flag[set]) & 0xFFFFFFFFull;
            #pragma unroll 1
            while (mask) {
                int col = (int)__builtin_ctzll(mask);
                mask &= mask - 1;
                int px = pw + set * 32 + col;                  // wave-uniform
                float a[8] = {0.f,0.f,0.f,0.f,0.f,0.f,0.f,0.f};
                float r[8] = {0.f,0.f,0.f,0.f,0.f,0.f,0.f,0.f};
                #pragma unroll 16
                for (int i = 0; i < CDIM; ++i) {
                    float zi = zt[i][px];                      // LDS broadcast
                    r[i & 7] += zi * zi;                       // ref: round square, then add
                    const float* ct = cbT + i * KCODES + lane;
                    #pragma unroll
                    for (int k = 0; k < 8; ++k)
                        a[k] = fmaf(zi, ct[k * 64], a[k]);     // sequential ascending i
                }
                float A = ((r[0] + r[1]) + (r[2] + r[3])) + ((r[4] + r[5]) + (r[6] + r[7]));
                float best = 3.4e38f; int bidx = 0x7FFFFFFF;
                #pragma unroll
                for (int k = 0; k < 8; ++k) {                  // idx = k*64+lane, ascending
                    float d = (A - 2.0f * a[k]) + c2r[k * 64 + lane];
                    if (d < best) { best = d; bidx = k * 64 + lane; }
                }
                for (int off = 32; off; off >>= 1) {
                    float ob = __shfl_down(best, off);
                    int   oi = __shfl_down(bidx, off);
                    if (ob < best || (ob == best && oi < bidx)) { best = ob; bidx = oi; }
                }
                bidx = __shfl(bidx, 0);
                if (c == col) idxv[set] = bidx;
            }
        }
    }

    // idx out (contiguous) + idx to LDS for phase C
    {
        int pl = pw + h * 32 + c;
        int own = h ? idxv[1] : idxv[0];
        out[IDXOUT_OFF + pxblk + pl] = (float)own;
        idxs[pl] = own;
    }

    // loss (z_q written in phase C); same numerics as Round 8
    float lsum = 0.f;
    #pragma unroll
    for (int set = 0; set < 2; ++set) {
        const float* crow = cb + (size_t)idxv[set] * CDIM;
        #pragma unroll
        for (int s = 0; s < 4; ++s) {
            int ch0 = s * 16 + h * 8;
            f32x4 g0 = *(const f32x4*)(crow + ch0);
            f32x4 g1 = *(const f32x4*)(crow + ch0 + 4);
            #pragma unroll
            for (int j = 0; j < 8; ++j) {
                float zq = (j < 4) ? g0[j] : g1[j - 4];
                float zv = (bf2f(zh[set][s][j]) + bf2f(zl[set][s][j])) * -2.44140625e-4f;
                float d = zq - zv;
                lsum = fmaf(d, d, lsum);
            }
        }
    }
    double dl = (double)lsum;
    for (int off = 32; off; off >>= 1) dl += __shfl_down(dl, off);
    if (lane == 0) wls[wav] = dl;

    __syncthreads();
    if (tid == 0) atomicAdd((double*)ws, (wls[0] + wls[1]) + (wls[2] + wls[3]));

    // ---- Phase C: streaming z_q write (1KB contiguous per channel stream)
    {
        int px4 = lane * 4;
        i32x4 i4 = *(const i32x4*)&idxs[px4];
        float* obase = out + (size_t)b * B_STRIDE + hw0;
        #pragma unroll
        for (int p = 0; p < 16; ++p) {
            int ch = p * 4 + wav;
            f32x4 v;
            v[0] = cb[(size_t)i4[0] * CDIM + ch];
            v[1] = cb[(size_t)i4[1] * CDIM + ch];
            v[2] = cb[(size_t)i4[2] * CDIM + ch];
            v[3] = cb[(size_t)i4[3] * CDIM + ch];
            *(f32x4*)(obase + (size_t)ch * CH_STRIDE + px4) = v;
        }
    }
}

__global__ void k4_loss(float* __restrict__ out, const double* __restrict__ loss_acc) {
    out[LOSS_OFF] = (float)(1.25 * (*loss_acc) / (double)ZQ_SIZE);
}

extern "C" void kernel_launch(void* const* d_in, const int* in_sizes, int n_in,
                              void* d_out, int out_size, void* d_ws, size_t ws_size,
                              hipStream_t stream) {
    const float* z_e = (const float*)d_in[0];
    const float* cb  = (const float*)d_in[1];
    float* out = (float*)d_out;
    char* ws = (char*)d_ws;

    hipMemsetAsync(d_ws, 0, 64, stream);
    k0_prep<<<1, 512, 0, stream>>>(cb, ws);
    k1_mfma<<<NPIX / 256, 256, 69664, stream>>>(z_e, cb, ws, out);
    k4_loss<<<1, 1, 0, stream>>>(out, (const double*)ws);
}

// Round 12
// 187.903 us; speedup vs baseline: 1.3706x; 1.3706x over previous
//
#include <hip/hip_runtime.h>
#include <hip/hip_bf16.h>
#include <stdint.h>

// z_e (32,64,64,64) f32, codebook (512,64) f32.
// d_out (f32): [0..8388607] z_q (B,C,H,W); [8388608] loss; [8388609..] indices as float.
#define NPIX 131072
#define CDIM 64
#define KCODES 512
#define ZQ_SIZE 8388608
#define LOSS_OFF 8388608
#define IDXOUT_OFF 8388609
#define CH_STRIDE 4096
#define B_STRIDE 262144
#define MARGIN_UNITS 160       // > 2*ulp(A)(=64u) + MFMA err(~5u) safety; ~3.8e-5 gap
#define SCALE 4194304.0f       // 2^22
#define BIAS 0.5f

typedef __attribute__((ext_vector_type(8))) short short8v;   // 8 bf16
typedef __attribute__((ext_vector_type(16))) float f32x16;
typedef __attribute__((ext_vector_type(4))) float f32x4;
typedef __attribute__((ext_vector_type(4))) int i32x4;

// ws layout:
//   0       double loss
//   64      float  c2_ref[512]   (numpy pairwise-8 order, for exact resolve)
//   2112    float  c2fix[512]    ((||c||^2 + 0.5) * 2^22)
//   4160    ushort cb_hi chunks  [g][code][8 bf16], scaled 2^11  (65536 B)
//   69696   ushort cb_lo chunks  same layout, residual            (65536 B)
//   135232  float  cbT[64][512]  transposed f32 codebook (131072 B)
#define WS_C2REF 64
#define WS_C2FIX 2112
#define WS_CBHI  4160
#define WS_CBLO  69696
#define WS_CBT   135232

// LDS layout (dynamic):
//   0      float zt[64][260]     66560 B
//   66560  int   idxs[256]        1024 B
//   67584  int   queue[256]       1024 B
//   68608  int   qcnt                4 B  (+4 pad)
#define L_IDXS 66560
#define L_QUEUE 67584
#define L_QCNT 68608
#define LDS_SZ 68616

__device__ __forceinline__ uint32_t f2bf_rne(float v) {
    uint32_t u = __float_as_uint(v);
    return (u + 0x7FFFu + ((u >> 16) & 1u)) >> 16;
}
__device__ __forceinline__ float bf2f(short s) {
    return __uint_as_float(((uint32_t)(unsigned short)s) << 16);
}

__global__ void k0_prep(const float* __restrict__ cb, char* __restrict__ ws) {
#pragma clang fp contract(off)
    int k = threadIdx.x;
    if (k >= KCODES) return;
    const float* cr = cb + (size_t)k * CDIM;
    float r[8];
    #pragma unroll
    for (int j = 0; j < 8; ++j) r[j] = cr[j] * cr[j];
    #pragma unroll
    for (int t = 1; t < 8; ++t)
        #pragma unroll
        for (int j = 0; j < 8; ++j) r[j] += cr[8 * t + j] * cr[8 * t + j];
    ((float*)(ws + WS_C2REF))[k] = ((r[0] + r[1]) + (r[2] + r[3])) + ((r[4] + r[5]) + (r[6] + r[7]));
    float acc = 0.f;
    #pragma unroll
    for (int i = 0; i < CDIM; ++i) acc = fmaf(cr[i], cr[i], acc);
    ((float*)(ws + WS_C2FIX))[k] = (acc + BIAS) * SCALE;
    unsigned short* hi = (unsigned short*)(ws + WS_CBHI);
    unsigned short* lo = (unsigned short*)(ws + WS_CBLO);
    #pragma unroll
    for (int g = 0; g < 8; ++g)
        #pragma unroll
        for (int j = 0; j < 8; ++j) {
            float cs = cr[g * 8 + j] * 2048.0f;
            uint32_t uh = f2bf_rne(cs);
            float l = cs - bf2f((short)uh);
            size_t o = ((size_t)(g * KCODES + k)) * 8 + j;
            hi[o] = (unsigned short)uh;
            lo[o] = (unsigned short)f2bf_rne(l);
        }
    float* cbT = (float*)(ws + WS_CBT);
    #pragma unroll
    for (int i = 0; i < CDIM; ++i) cbT[i * KCODES + k] = cr[i];
}

// Block = 256 contiguous pixels, 4 waves. R10 structure + block-batched resolve.
__global__ __launch_bounds__(256, 2) void k1_mfma(const float* __restrict__ z_e,
                                                  const float* __restrict__ cb,
                                                  char* __restrict__ ws,
                                                  float* __restrict__ out) {
#pragma clang fp contract(off)
    extern __shared__ char smem[];
    float (*zt)[260] = (float (*)[260])smem;
    int* idxs  = (int*)(smem + L_IDXS);
    int* queue = (int*)(smem + L_QUEUE);
    int* qcnt  = (int*)(smem + L_QCNT);

    const int tid  = threadIdx.x;
    const int lane = tid & 63;
    const int wav  = tid >> 6;
    const int h    = lane >> 5;
    const int c    = lane & 31;

    const int pxblk = blockIdx.x * 256;
    const int b     = pxblk >> 12;
    const int hw0   = pxblk & 4095;
    const float* zbase = z_e + (size_t)b * B_STRIDE + hw0;

    // ---- Phase A: stage z tile (64ch x 256px) to LDS
    if (tid == 0) *qcnt = 0;
    {
        int px4 = lane * 4;
        #pragma unroll
        for (int p = 0; p < 16; ++p) {
            int ch = p * 4 + wav;
            f32x4 v = *(const f32x4*)(zbase + (size_t)ch * CH_STRIDE + px4);
            *(f32x4*)&zt[ch][px4] = v;
        }
    }
    __syncthreads();

    // ---- Phase B: MFMA scores + min-track (Round-8-verified math)
    const int pw = wav * 64;
    short8v zh[2][4], zl[2][4];
    #pragma unroll
    for (int set = 0; set < 2; ++set) {
        int px = pw + set * 32 + c;
        #pragma unroll
        for (int s = 0; s < 4; ++s) {
            short8v vh, vl;
            #pragma unroll
            for (int j = 0; j < 8; ++j) {
                float zs = zt[s * 16 + h * 8 + j][px] * -4096.0f;
                uint32_t uh = f2bf_rne(zs);
                float l = zs - bf2f((short)uh);
                vh[j] = (short)uh;
                vl[j] = (short)f2bf_rne(l);
            }
            zh[set][s] = vh; zl[set][s] = vl;
        }
    }

    const short8v* hi_chunks = (const short8v*)(ws + WS_CBHI);
    const short8v* lo_chunks = (const short8v*)(ws + WS_CBLO);
    const float* c2f = (const float*)(ws + WS_C2FIX);
    uint32_t m1[2] = {0xFFFFFFFFu, 0xFFFFFFFFu};
    uint32_t m2[2] = {0xFFFFFFFFu, 0xFFFFFFFFu};

    for (int t = 0; t < 16; ++t) {
        short8v a[4], al[4];
        #pragma unroll
        for (int s = 0; s < 4; ++s) {
            int chunk = (2 * s + h) * KCODES + t * 32 + c;
            a[s]  = hi_chunks[chunk];
            al[s] = lo_chunks[chunk];
        }
        int rbase = t * 32 + 4 * h;
        f32x4 q0 = *(const f32x4*)(c2f + rbase + 0);
        f32x4 q1 = *(const f32x4*)(c2f + rbase + 8);
        f32x4 q2 = *(const f32x4*)(c2f + rbase + 16);
        f32x4 q3 = *(const f32x4*)(c2f + rbase + 24);

        #pragma unroll
        for (int set = 0; set < 2; ++set) {
            f32x16 acc;
            #pragma unroll
            for (int i = 0; i < 4; ++i) {
                acc[i] = q0[i]; acc[4 + i] = q1[i]; acc[8 + i] = q2[i]; acc[12 + i] = q3[i];
            }
            #pragma unroll
            for (int s = 0; s < 4; ++s)
                acc = __builtin_amdgcn_mfma_f32_32x32x16_bf16(a[s], zh[set][s], acc, 0, 0, 0);
            #pragma unroll
            for (int s = 0; s < 4; ++s)
                acc = __builtin_amdgcn_mfma_f32_32x32x16_bf16(a[s], zl[set][s], acc, 0, 0, 0);
            #pragma unroll
            for (int s = 0; s < 4; ++s)
                acc = __builtin_amdgcn_mfma_f32_32x32x16_bf16(al[s], zh[set][s], acc, 0, 0, 0);
            #pragma unroll
            for (int i = 0; i < 16; ++i) {
                uint32_t code = (uint32_t)(t * 32 + 4 * h + (i & 3) + 8 * (i >> 2));
                uint32_t u = (((uint32_t)acc[i]) << 9) | code;
                uint32_t mx = m1[set] > u ? m1[set] : u;
                m2[set] = m2[set] < mx ? m2[set] : mx;
                m1[set] = m1[set] < u ? m1[set] : u;
            }
        }
    }

    #pragma unroll
    for (int set = 0; set < 2; ++set) {
        uint32_t o1 = (uint32_t)__shfl_xor((int)m1[set], 32);
        uint32_t o2 = (uint32_t)__shfl_xor((int)m2[set], 32);
        uint32_t mx  = m1[set] > o1 ? m1[set] : o1;
        uint32_t mn2 = m2[set] < o2 ? m2[set] : o2;
        m2[set] = mn2 < mx ? mn2 : mx;
        m1[set] = m1[set] < o1 ? m1[set] : o1;
    }

    // provisional idx to LDS + flagged pixels into block queue (owner lane per set)
    #pragma unroll
    for (int set = 0; set < 2; ++set) {
        if (h == set) {
            int pl = pw + set * 32 + c;
            idxs[pl] = (int)(m1[set] & 0x1FFu);
            if ((int)((m2[set] >> 9) - (m1[set] >> 9)) < MARGIN_UNITS) {
                int pos = atomicAdd(qcnt, 1);
                queue[pos] = pl;
            }
        }
    }
    __syncthreads();

    // ---- Batched exact resolve (reference f32 math), one queue entry per wave.
    // z prefetched to registers (no serial load-use chain); cbT loads coalesced.
    {
        const float* c2r = (const float*)(ws + WS_C2REF);
        const float* cbT = (const float*)(ws + WS_CBT);
        const int nf = *qcnt;
        #pragma unroll 1
        for (int q = wav; q < nf; q += 4) {
            int pl = queue[q];
            float zr[CDIM];
            #pragma unroll
            for (int i = 0; i < CDIM; ++i) zr[i] = zt[i][pl];   // LDS broadcast, independent
            float r[8] = {0.f,0.f,0.f,0.f,0.f,0.f,0.f,0.f};
            #pragma unroll
            for (int i = 0; i < CDIM; ++i) r[i & 7] += zr[i] * zr[i];
            float A = ((r[0] + r[1]) + (r[2] + r[3])) + ((r[4] + r[5]) + (r[6] + r[7]));
            float a[8] = {0.f,0.f,0.f,0.f,0.f,0.f,0.f,0.f};
            #pragma unroll 8
            for (int i = 0; i < CDIM; ++i) {
                const float* ct = cbT + i * KCODES + lane;
                #pragma unroll
                for (int k = 0; k < 8; ++k)
                    a[k] = fmaf(zr[i], ct[k * 64], a[k]);       // ascending i per code
            }
            float best = 3.4e38f; int bidx = 0x7FFFFFFF;
            #pragma unroll
            for (int k = 0; k < 8; ++k) {                        // idx = k*64+lane
                float d = (A - 2.0f * a[k]) + c2r[k * 64 + lane];
                if (d < best) { best = d; bidx = k * 64 + lane; }
            }
            for (int off = 32; off; off >>= 1) {
                float ob = __shfl_down(best, off);
                int   oi = __shfl_down(bidx, off);
                if (ob < best || (ob == best && oi < bidx)) { best = ob; bidx = oi; }
            }
            if (lane == 0) idxs[pl] = bidx;
        }
    }
    __syncthreads();

    // ---- Epilogue 1: per-thread pixel tid — idx out + loss (final indices)
    {
        int idx = idxs[tid];
        out[IDXOUT_OFF + pxblk + tid] = (float)idx;
        const float* crow = cb + (size_t)idx * CDIM;
        float lsum = 0.f;
        #pragma unroll
        for (int s = 0; s < 16; ++s) {
            f32x4 g = *(const f32x4*)(crow + s * 4);
            #pragma unroll
            for (int j = 0; j < 4; ++j) {
                float d = g[j] - zt[s * 4 + j][tid];            // conflict-free (lane-consecutive)
                lsum = fmaf(d, d, lsum);
            }
        }
        double dl = (double)lsum;
        for (int off = 32; off; off >>= 1) dl += __shfl_down(dl, off);
        if (lane == 0) atomicAdd((double*)ws, dl);
    }

    // ---- Epilogue 2: streaming z_q write (1KB contiguous per channel stream)
    {
        int px4 = lane * 4;
        i32x4 i4 = *(const i32x4*)&idxs[px4];
        float* obase = out + (size_t)b * B_STRIDE + hw0;
        #pragma unroll
        for (int p = 0; p < 16; ++p) {
            int ch = p * 4 + wav;
            f32x4 v;
            v[0] = cb[(size_t)i4[0] * CDIM + ch];
            v[1] = cb[(size_t)i4[1] * CDIM + ch];
            v[2] = cb[(size_t)i4[2] * CDIM + ch];
            v[3] = cb[(size_t)i4[3] * CDIM + ch];
            *(f32x4*)(obase + (size_t)ch * CH_STRIDE + px4) = v;
        }
    }
}

__global__ void k4_loss(float* __restrict__ out, const double* __restrict__ loss_acc) {
    out[LOSS_OFF] = (float)(1.25 * (*loss_acc) / (double)ZQ_SIZE);
}

extern "C" void kernel_launch(void* const* d_in, const int* in_sizes, int n_in,
                              void* d_out, int out_size, void* d_ws, size_t ws_size,
                              hipStream_t stream) {
    const float* z_e = (const float*)d_in[0];
    const float* cb  = (const float*)d_in[1];
    float* out = (float*)d_out;
    char* ws = (char*)d_ws;

    hipMemsetAsync(d_ws, 0, 64, stream);
    k0_prep<<<1, 512, 0, stream>>>(cb, ws);
    k1_mfma<<<NPIX / 256, 256, LDS_SZ, stream>>>(z_e, cb, ws, out);
    k4_loss<<<1, 1, 0, stream>>>(out, (const double*)ws);
}

// Round 13
// 136.129 us; speedup vs baseline: 1.8920x; 1.3803x over previous
//
#include <hip/hip_runtime.h>
#include <hip/hip_bf16.h>
#include <stdint.h>

// z_e (32,64,64,64) f32, codebook (512,64) f32.
// d_out (f32): [0..8388607] z_q (B,C,H,W); [8388608] loss; [8388609..] indices as float.
#define NPIX 131072
#define CDIM 64
#define KCODES 512
#define ZQ_SIZE 8388608
#define LOSS_OFF 8388608
#define IDXOUT_OFF 8388609
#define CH_STRIDE 4096
#define B_STRIDE 262144
#define MARGIN_UNITS 256       // 6.1e-5 gap: covers ref f32 grid noise (R6-verified)
#define SCALE 4194304.0f       // 2^22
#define BIAS 0.5f

typedef __attribute__((ext_vector_type(8))) short short8v;   // 8 bf16
typedef __attribute__((ext_vector_type(16))) float f32x16;
typedef __attribute__((ext_vector_type(4))) float f32x4;

// ws layout:
//   0       double loss
//   64      float  c2_ref[512]
//   2112    float  c2fix[512]
//   4160    ushort cb_hi chunks [g][code][8 bf16] (65536 B)   (hi+lo contiguous 128KB)
//   69696   ushort cb_lo chunks (65536 B)
//   135232  float  cbT[64][512] (131072 B)
#define WS_C2REF 64
#define WS_C2FIX 2112
#define WS_CBHI  4160
#define WS_CBLO  69696
#define WS_CBT   135232

// LDS layout:
#define L_CBHI  0          // 65536
#define L_CBLO  65536      // 65536
#define L_C2F   131072     // 2048
#define L_QUEUE 133120     // int[512]
#define L_QCNT  135168     // int (+pad)
#define L_WLS   135232     // double[16]
#define L_IDXS  135360     // int[512]
#define LDS_SZ  137408

__device__ __forceinline__ uint32_t f2bf_rne(float v) {
    uint32_t u = __float_as_uint(v);
    return (u + 0x7FFFu + ((u >> 16) & 1u)) >> 16;
}
__device__ __forceinline__ float bf2f(short s) {
    return __uint_as_float(((uint32_t)(unsigned short)s) << 16);
}

__global__ void k0_prep(const float* __restrict__ cb, char* __restrict__ ws) {
#pragma clang fp contract(off)
    int k = blockIdx.x * 64 + threadIdx.x;
    if (k >= KCODES) return;
    const float* cr = cb + (size_t)k * CDIM;
    float r[8];
    #pragma unroll
    for (int j = 0; j < 8; ++j) r[j] = cr[j] * cr[j];
    #pragma unroll
    for (int t = 1; t < 8; ++t)
        #pragma unroll
        for (int j = 0; j < 8; ++j) r[j] += cr[8 * t + j] * cr[8 * t + j];
    ((float*)(ws + WS_C2REF))[k] = ((r[0] + r[1]) + (r[2] + r[3])) + ((r[4] + r[5]) + (r[6] + r[7]));
    float acc = 0.f;
    #pragma unroll
    for (int i = 0; i < CDIM; ++i) acc = fmaf(cr[i], cr[i], acc);
    ((float*)(ws + WS_C2FIX))[k] = (acc + BIAS) * SCALE;
    unsigned short* hi = (unsigned short*)(ws + WS_CBHI);
    unsigned short* lo = (unsigned short*)(ws + WS_CBLO);
    #pragma unroll
    for (int g = 0; g < 8; ++g)
        #pragma unroll
        for (int j = 0; j < 8; ++j) {
            float cs = cr[g * 8 + j] * 2048.0f;
            uint32_t uh = f2bf_rne(cs);
            float l = cs - bf2f((short)uh);
            size_t o = ((size_t)(g * KCODES + k)) * 8 + j;
            hi[o] = (unsigned short)uh;
            lo[o] = (unsigned short)f2bf_rne(l);
        }
    float* cbT = (float*)(ws + WS_CBT);
    #pragma unroll
    for (int i = 0; i < CDIM; ++i) cbT[i * KCODES + k] = cr[i];
}

// 1024 threads = 16 waves, 512 contiguous pixels/block, 32 px/wave.
// Whole split codebook in LDS; 1 block/CU (LDS-capped), 4 waves/SIMD.
__global__ __launch_bounds__(1024) void k1_mfma(const float* __restrict__ z_e,
                                                const float* __restrict__ cb,
                                                char* __restrict__ ws,
                                                float* __restrict__ out) {
#pragma clang fp contract(off)
    extern __shared__ char smem[];
    int*    queue = (int*)(smem + L_QUEUE);
    int*    qcnt  = (int*)(smem + L_QCNT);
    double* wls   = (double*)(smem + L_WLS);
    int*    idxs  = (int*)(smem + L_IDXS);

    const int tid  = threadIdx.x;
    const int lane = tid & 63;
    const int wav  = tid >> 6;          // 0..15
    const int h    = lane >> 5;
    const int c    = lane & 31;

    const int pxblk = blockIdx.x * 512;
    const int b     = pxblk >> 12;
    const int hwb   = pxblk & 4095;
    const float* zb = z_e + (size_t)b * B_STRIDE;

    // ---- stage codebook hi+lo (128KB contiguous) + c2fix to LDS
    if (tid == 0) *qcnt = 0;
    {
        const uint4* src = (const uint4*)(ws + WS_CBHI);
        uint4* dst = (uint4*)smem;
        #pragma unroll
        for (int i = 0; i < 8; ++i)
            dst[i * 1024 + tid] = src[i * 1024 + tid];
        if (tid < 128)
            ((uint4*)(smem + L_C2F))[tid] = ((const uint4*)(ws + WS_C2FIX))[tid];
    }
    __syncthreads();

    // ---- z fragment loads (batched into regs first, then bf16 split)
    const int lpx = wav * 32 + c;        // block-local pixel
    const int hw  = hwb + lpx;
    float zf[32];
    #pragma unroll
    for (int s = 0; s < 4; ++s)
        #pragma unroll
        for (int j = 0; j < 8; ++j)
            zf[s * 8 + j] = zb[(size_t)(s * 16 + h * 8 + j) * CH_STRIDE + hw];

    short8v zh[4], zl[4];
    #pragma unroll
    for (int s = 0; s < 4; ++s) {
        short8v vh, vl;
        #pragma unroll
        for (int j = 0; j < 8; ++j) {
            float zs = zf[s * 8 + j] * -4096.0f;
            uint32_t uh = f2bf_rne(zs);
            float l = zs - bf2f((short)uh);
            vh[j] = (short)uh;
            vl[j] = (short)f2bf_rne(l);
        }
        zh[s] = vh; zl[s] = vl;
    }

    // ---- MFMA scores + min-track (R8-verified math), codebook from LDS
    const float* c2f = (const float*)(smem + L_C2F);
    uint32_t m1 = 0xFFFFFFFFu, m2 = 0xFFFFFFFFu;

    for (int t = 0; t < 16; ++t) {
        short8v a[4], al[4];
        #pragma unroll
        for (int s = 0; s < 4; ++s) {
            int chunk = (2 * s + h) * KCODES + t * 32 + c;
            a[s]  = *(const short8v*)(smem + L_CBHI + (size_t)chunk * 16);
            al[s] = *(const short8v*)(smem + L_CBLO + (size_t)chunk * 16);
        }
        int rbase = t * 32 + 4 * h;
        f32x4 q0 = *(const f32x4*)(c2f + rbase + 0);
        f32x4 q1 = *(const f32x4*)(c2f + rbase + 8);
        f32x4 q2 = *(const f32x4*)(c2f + rbase + 16);
        f32x4 q3 = *(const f32x4*)(c2f + rbase + 24);

        f32x16 acc;
        #pragma unroll
        for (int i = 0; i < 4; ++i) {
            acc[i] = q0[i]; acc[4 + i] = q1[i]; acc[8 + i] = q2[i]; acc[12 + i] = q3[i];
        }
        #pragma unroll
        for (int s = 0; s < 4; ++s)
            acc = __builtin_amdgcn_mfma_f32_32x32x16_bf16(a[s], zh[s], acc, 0, 0, 0);
        #pragma unroll
        for (int s = 0; s < 4; ++s)
            acc = __builtin_amdgcn_mfma_f32_32x32x16_bf16(a[s], zl[s], acc, 0, 0, 0);
        #pragma unroll
        for (int s = 0; s < 4; ++s)
            acc = __builtin_amdgcn_mfma_f32_32x32x16_bf16(al[s], zh[s], acc, 0, 0, 0);
        #pragma unroll
        for (int i = 0; i < 16; ++i) {
            uint32_t code = (uint32_t)(t * 32 + 4 * h + (i & 3) + 8 * (i >> 2));
            uint32_t u = (((uint32_t)acc[i]) << 9) | code;
            uint32_t mx = m1 > u ? m1 : u;
            m2 = m2 < mx ? m2 : mx;
            m1 = m1 < u ? m1 : u;
        }
    }

    {   // merge lanes l and l^32 (same pixel)
        uint32_t o1 = (uint32_t)__shfl_xor((int)m1, 32);
        uint32_t o2 = (uint32_t)__shfl_xor((int)m2, 32);
        uint32_t mx  = m1 > o1 ? m1 : o1;
        uint32_t mn2 = m2 < o2 ? m2 : o2;
        m2 = mn2 < mx ? mn2 : mx;
        m1 = m1 < o1 ? m1 : o1;
    }

    // provisional idx + flag queue (owner lane h==0)
    if (h == 0) {
        idxs[lpx] = (int)(m1 & 0x1FFu);
        if ((int)((m2 >> 9) - (m1 >> 9)) < MARGIN_UNITS) {
            int pos = atomicAdd(qcnt, 1);
            queue[pos] = lpx;
        }
    }
    __syncthreads();

    // ---- batched exact resolve (R12-verified reference math), queue over 16 waves
    {
        const float* c2r = (const float*)(ws + WS_C2REF);
        const float* cbT = (const float*)(ws + WS_CBT);
        const int nf = *qcnt;
        #pragma unroll 1
        for (int q = wav; q < nf; q += 16) {
            int pl = queue[q];
            int hwq = hwb + pl;
            float zr[CDIM];
            #pragma unroll
            for (int i = 0; i < CDIM; ++i) zr[i] = zb[(size_t)i * CH_STRIDE + hwq]; // uniform, L3-hot
            float r[8] = {0.f,0.f,0.f,0.f,0.f,0.f,0.f,0.f};
            #pragma unroll
            for (int i = 0; i < CDIM; ++i) r[i & 7] += zr[i] * zr[i];
            float A = ((r[0] + r[1]) + (r[2] + r[3])) + ((r[4] + r[5]) + (r[6] + r[7]));
            float a[8] = {0.f,0.f,0.f,0.f,0.f,0.f,0.f,0.f};
            #pragma unroll 8
            for (int i = 0; i < CDIM; ++i) {
                const float* ct = cbT + i * KCODES + lane;
                #pragma unroll
                for (int k = 0; k < 8; ++k)
                    a[k] = fmaf(zr[i], ct[k * 64], a[k]);
            }
            float best = 3.4e38f; int bidx = 0x7FFFFFFF;
            #pragma unroll
            for (int k = 0; k < 8; ++k) {
                float d = (A - 2.0f * a[k]) + c2r[k * 64 + lane];
                if (d < best) { best = d; bidx = k * 64 + lane; }
            }
            for (int off = 32; off; off >>= 1) {
                float ob = __shfl_down(best, off);
                int   oi = __shfl_down(bidx, off);
                if (ob < best || (ob == best && oi < bidx)) { best = ob; bidx = oi; }
            }
            if (lane == 0) idxs[pl] = bidx;
        }
    }
    __syncthreads();

    // ---- epilogue: idx out + z_q + loss (final indices from LDS)
    int idxv = idxs[lpx];
    if (h == 0) out[IDXOUT_OFF + pxblk + lpx] = (float)idxv;

    float lsum = 0.f;
    {
        const float* crow = cb + (size_t)idxv * CDIM;
        float* ob = out + (size_t)b * B_STRIDE + hw;
        #pragma unroll
        for (int s = 0; s < 4; ++s) {
            int ch0 = s * 16 + h * 8;
            f32x4 g0 = *(const f32x4*)(crow + ch0);
            f32x4 g1 = *(const f32x4*)(crow + ch0 + 4);
            #pragma unroll
            for (int j = 0; j < 8; ++j) {
                float zq = (j < 4) ? g0[j] : g1[j - 4];
                float zv = (bf2f(zh[s][j]) + bf2f(zl[s][j])) * -2.44140625e-4f;
                ob[(size_t)(ch0 + j) * CH_STRIDE] = zq;
                float d = zq - zv;
                lsum = fmaf(d, d, lsum);
            }
        }
    }
    double dl = (double)lsum;
    for (int off = 32; off; off >>= 1) dl += __shfl_down(dl, off);
    if (lane == 0) wls[wav] = dl;
    __syncthreads();
    if (tid == 0) {
        double s = 0.0;
        #pragma unroll
        for (int i = 0; i < 16; ++i) s += wls[i];
        atomicAdd((double*)ws, s);
    }
}

__global__ void k4_loss(float* __restrict__ out, const double* __restrict__ loss_acc) {
    out[LOSS_OFF] = (float)(1.25 * (*loss_acc) / (double)ZQ_SIZE);
}

extern "C" void kernel_launch(void* const* d_in, const int* in_sizes, int n_in,
                              void* d_out, int out_size, void* d_ws, size_t ws_size,
                              hipStream_t stream) {
    const float* z_e = (const float*)d_in[0];
    const float* cb  = (const float*)d_in[1];
    float* out = (float*)d_out;
    char* ws = (char*)d_ws;

    hipMemsetAsync(d_ws, 0, 64, stream);
    k0_prep<<<8, 64, 0, stream>>>(cb, ws);
    k1_mfma<<<NPIX / 512, 1024, LDS_SZ, stream>>>(z_e, cb, ws, out);
    k4_loss<<<1, 1, 0, stream>>>(out, (const double*)ws);
}